// Round 2
// baseline (621.772 us; speedup 1.0000x reference)
//
#include <hip/hip_runtime.h>

#define EPS 1e-4f
#define D 64
#define NCASES 8
#define TILE_ROWS 64

typedef __attribute__((ext_vector_type(8))) short short8;
typedef __attribute__((ext_vector_type(4))) float f32x4;

// ws layout (float units):
//   [0, 4096)     Wsum fp32, row-major [i][j]   (i = input dim, j = output col)
//   [4096, 4160)  bsum fp32
//   [4160, 6208)  WhT bf16 (ushort[64][64], [j][i] = B^T so B-frag loads are contiguous)
//   [6208, 8256)  WlT bf16 (ushort[64][64])
// ---------------------------------------------------------------------------
__global__ void prep_sums(const float* __restrict__ W, const float* __restrict__ b,
                          float* __restrict__ ws) {
  int idx = blockIdx.x * blockDim.x + threadIdx.x;
  float* wsum = ws;
  float* bsum = ws + D * D;
  unsigned short* WhT = (unsigned short*)(ws + D * D + D);
  unsigned short* WlT = WhT + D * D;
  if (idx < D * D) {
    int i = idx >> 6, j = idx & 63;
    float s = 0.f;
#pragma unroll
    for (int c = 0; c < NCASES; ++c) s += W[c * D * D + idx];
    wsum[idx] = s;
    // truncation split: s = sh + r, sh exactly representable in bf16
    unsigned int bits = __float_as_uint(s);
    float sh = __uint_as_float(bits & 0xffff0000u);
    float r = s - sh;  // exact (same-exponent subtraction)
    WhT[j * D + i] = (unsigned short)(bits >> 16);
    WlT[j * D + i] = (unsigned short)(__float_as_uint(r) >> 16);
  } else if (idx < D * D + D) {
    int j = idx - D * D;
    float s = 0.f;
#pragma unroll
    for (int c = 0; c < NCASES; ++c) s += b[c * D + j];
    bsum[j] = s;
  }
}

// ---------------------------------------------------------------------------
// Main kernel: out[N x 64] = X @ Wsum + bsum as 3-pass bf16-split MFMA GEMM.
//   block = 256 threads = 4 waves, tile = 64 rows.
//   wave w computes M-tile w (16 rows x 64 cols): 4 N-tiles x 2 K x 3 passes
//   = 24 x mfma_f32_16x16x32_bf16, B fragments resident in VGPRs.
// Rows with any inactive case (~8e-4): MFMA store is predicated OFF and
// threads 0..63 recompute the row in exact fp32 (race-free, no 2nd barrier).
// ---------------------------------------------------------------------------
__global__ __launch_bounds__(256, 3) void guarded_layer(
    const float* __restrict__ x, const float* __restrict__ presence,
    const float* __restrict__ W, const float* __restrict__ b,
    const float* __restrict__ ws, float* __restrict__ out, int N) {
  const float* wsum = ws;
  const float* bsum = ws + D * D;
  const unsigned short* WhT = (const unsigned short*)(ws + D * D + D);
  const unsigned short* WlT = WhT + D * D;

  // A tiles in bf16 (hi/lo), row-major [row][k], 128 B/row, XOR-swizzled
  // (byte ^= (row&7)<<4) so MFMA ds_read_b128 is 2-way (free) not 16-way.
  __shared__ __align__(16) unsigned int Ah[TILE_ROWS * 32];  // 8 KB
  __shared__ __align__(16) unsigned int Al[TILE_ROWS * 32];  // 8 KB
  __shared__ int flags[TILE_ROWS];

  const int tid = threadIdx.x;
  const int lane = tid & 63;
  const long long r0 = (long long)blockIdx.x * TILE_ROWS;

  // ---- flat, perfectly-coalesced x loads: 1024 float4/tile, 4 per thread ----
  float4 v[4];
  const float4* x4 = reinterpret_cast<const float4*>(x);
  const long long tile_f4 = r0 * 16;
  const long long max_f4 = (long long)N * 16 - 1;
#pragma unroll
  for (int f = 0; f < 4; ++f) {
    long long g = tile_f4 + tid + f * 256;
    if (g > max_f4) g = max_f4;  // clamp: duplicate tail, never stored
    v[f] = x4[g];
  }

  // ---- B fragments + bsum (prefetched while x is in flight; L2-hot) ----
  const int n_l = lane & 15;  // output col within N-tile
  const int kg = lane >> 4;   // k-group
  short8 bh[4][2], bl[4][2];
  float bs[4];
#pragma unroll
  for (int nt = 0; nt < 4; ++nt) {
    bs[nt] = bsum[nt * 16 + n_l];
#pragma unroll
    for (int kb = 0; kb < 2; ++kb) {
      int off = (nt * 16 + n_l) * D + kb * 32 + kg * 8;  // ushort index
      bh[nt][kb] = *reinterpret_cast<const short8*>(WhT + off);
      bl[nt][kb] = *reinterpret_cast<const short8*>(WlT + off);
    }
  }

  // ---- presence flags (threads 0..63, one row each) ----
  if (tid < TILE_ROWS) {
    long long row = r0 + tid;
    if (row > (long long)N - 1) row = (long long)N - 1;
    const float4* p4 = reinterpret_cast<const float4*>(presence + row * NCASES);
    float4 pa = p4[0], pb = p4[1];
    float pmin = fminf(fminf(fminf(pa.x, pa.y), fminf(pa.z, pa.w)),
                       fminf(fminf(pb.x, pb.y), fminf(pb.z, pb.w)));
    flags[tid] = !(pmin > EPS);
  }

  // ---- convert fp32 -> bf16 hi/lo, swizzled LDS writes (ds_write_b64) ----
#pragma unroll
  for (int f = 0; f < 4; ++f) {
    int ti = tid + f * 256;  // tile float4 index (0..1023)
    int row = ti >> 4;
    int c16 = ti & 15;  // 8-byte chunk within the bf16 row
    unsigned int bx = __float_as_uint(v[f].x), by = __float_as_uint(v[f].y);
    unsigned int bz = __float_as_uint(v[f].z), bw = __float_as_uint(v[f].w);
    float rx = v[f].x - __uint_as_float(bx & 0xffff0000u);
    float ry = v[f].y - __uint_as_float(by & 0xffff0000u);
    float rz = v[f].z - __uint_as_float(bz & 0xffff0000u);
    float rw = v[f].w - __uint_as_float(bw & 0xffff0000u);
    unsigned int h0 = (bx >> 16) | (by & 0xffff0000u);
    unsigned int h1 = (bz >> 16) | (bw & 0xffff0000u);
    unsigned int l0 = (__float_as_uint(rx) >> 16) | (__float_as_uint(ry) & 0xffff0000u);
    unsigned int l1 = (__float_as_uint(rz) >> 16) | (__float_as_uint(rw) & 0xffff0000u);
    int byte = row * 128 + c16 * 8;
    int sw = byte ^ ((row & 7) << 4);
    *reinterpret_cast<uint2*>((char*)Ah + sw) = make_uint2(h0, h1);
    *reinterpret_cast<uint2*>((char*)Al + sw) = make_uint2(l0, l1);
  }

  __syncthreads();

  // ---- MFMA: wave = M-tile, A frags from swizzled LDS (ds_read_b128) ----
  const int mtile = tid >> 6;
  const int ar = mtile * 16 + n_l;  // A row this lane reads (row = lane&15)
  short8 ah[2], al[2];
#pragma unroll
  for (int kb = 0; kb < 2; ++kb) {
    int byte = ar * 128 + kb * 64 + kg * 16;
    int sw = byte ^ ((ar & 7) << 4);
    ah[kb] = *reinterpret_cast<const short8*>((char*)Ah + sw);
    al[kb] = *reinterpret_cast<const short8*>((char*)Al + sw);
  }

  f32x4 acc[4];
#pragma unroll
  for (int nt = 0; nt < 4; ++nt) {
    acc[nt] = (f32x4){bs[nt], bs[nt], bs[nt], bs[nt]};
#pragma unroll
    for (int kb = 0; kb < 2; ++kb) {
      acc[nt] = __builtin_amdgcn_mfma_f32_16x16x32_bf16(ah[kb], bh[nt][kb], acc[nt], 0, 0, 0);
      acc[nt] = __builtin_amdgcn_mfma_f32_16x16x32_bf16(ah[kb], bl[nt][kb], acc[nt], 0, 0, 0);
      acc[nt] = __builtin_amdgcn_mfma_f32_16x16x32_bf16(al[kb], bh[nt][kb], acc[nt], 0, 0, 0);
    }
  }

  // ---- store: C layout col=lane&15, row=(lane>>4)*4+reg (m89-verified) ----
  const int rbase = mtile * 16 + kg * 4;
#pragma unroll
  for (int rg = 0; rg < 4; ++rg) {
    int rl = rbase + rg;
    long long row = r0 + rl;
    bool ok = (row < (long long)N) && !flags[rl];  // flagged rows: skip store
#pragma unroll
    for (int nt = 0; nt < 4; ++nt) {
      if (ok) __builtin_nontemporal_store(acc[nt][rg], out + row * D + nt * 16 + n_l);
    }
  }

  // ---- rare path: full fp32 recompute of flagged rows (threads 0..63) ----
  if (tid < TILE_ROWS && flags[tid]) {
    long long row = r0 + tid;
    if (row < (long long)N) {
      const float* xr = x + row * D;
#pragma unroll 1
      for (int jb = 0; jb < 4; ++jb) {  // 16 cols at a time caps registers
        float a[16];
#pragma unroll
        for (int j = 0; j < 16; ++j) a[j] = bsum[jb * 16 + j];
#pragma unroll 1
        for (int i = 0; i < D; ++i) {
          float xi = xr[i];
          const float* wr = wsum + i * D + jb * 16;
#pragma unroll
          for (int j = 0; j < 16; ++j) a[j] = fmaf(xi, wr[j], a[j]);
        }
#pragma unroll 1
        for (int c = 0; c < NCASES; ++c) {
          if (!(presence[row * NCASES + c] > EPS)) {
            const float* bc = b + c * D + jb * 16;
            const float* Wc = W + c * D * D;
#pragma unroll
            for (int j = 0; j < 16; ++j) a[j] -= bc[j];
#pragma unroll 1
            for (int i = 0; i < D; ++i) {
              float xi = xr[i];
              const float* wr = Wc + i * D + jb * 16;
#pragma unroll
              for (int j = 0; j < 16; ++j) a[j] = fmaf(-xi, wr[j], a[j]);
            }
          }
        }
        float4* o = reinterpret_cast<float4*>(out + row * D + jb * 16);
#pragma unroll
        for (int q = 0; q < 4; ++q)
          o[q] = make_float4(a[4 * q], a[4 * q + 1], a[4 * q + 2], a[4 * q + 3]);
      }
    }
  }
}

extern "C" void kernel_launch(void* const* d_in, const int* in_sizes, int n_in,
                              void* d_out, int out_size, void* d_ws, size_t ws_size,
                              hipStream_t stream) {
  const float* x = (const float*)d_in[0];
  const float* presence = (const float*)d_in[1];
  const float* W = (const float*)d_in[2];
  const float* b = (const float*)d_in[3];
  float* out = (float*)d_out;
  float* ws = (float*)d_ws;

  int N = in_sizes[0] / D;

  prep_sums<<<(D * D + D + 255) / 256, 256, 0, stream>>>(W, b, ws);

  int nblocks = (N + TILE_ROWS - 1) / TILE_ROWS;
  guarded_layer<<<nblocks, 256, 0, stream>>>(x, presence, W, b, ws, out, N);
}

// Round 3
// 592.495 us; speedup vs baseline: 1.0494x; 1.0494x over previous
//
#include <hip/hip_runtime.h>

#define EPS 1e-4f
#define D 64
#define NCASES 8
#define NBLOCKS 1024  // 4096 persistent waves = 16 waves/CU

typedef __attribute__((ext_vector_type(8))) short short8;
typedef __attribute__((ext_vector_type(4))) float f32x4;

// ws layout (float units):
//   [0, 4096)     Wsum fp32, row-major [i][j]
//   [4096, 4160)  bsum fp32
//   [4160, 6208)  WhT bf16 RNE (ushort[64][64], [j][i] = B^T, contiguous in k)
// ---------------------------------------------------------------------------
__global__ void prep_sums(const float* __restrict__ W, const float* __restrict__ b,
                          float* __restrict__ ws) {
  int idx = blockIdx.x * blockDim.x + threadIdx.x;
  float* wsum = ws;
  float* bsum = ws + D * D;
  unsigned short* WhT = (unsigned short*)(ws + D * D + D);
  if (idx < D * D) {
    int i = idx >> 6, j = idx & 63;
    float s = 0.f;
#pragma unroll
    for (int c = 0; c < NCASES; ++c) s += W[c * D * D + idx];
    wsum[idx] = s;
    // round-to-nearest-even bf16: |W - bf16(W)| <= 2^-9 |W|
    unsigned int bits = __float_as_uint(s);
    unsigned int rne = bits + 0x7fffu + ((bits >> 16) & 1u);
    WhT[j * D + i] = (unsigned short)(rne >> 16);
  } else if (idx < D * D + D) {
    int j = idx - D * D;
    float s = 0.f;
#pragma unroll
    for (int c = 0; c < NCASES; ++c) s += b[c * D + j];
    bsum[j] = s;
  }
}

// ---------------------------------------------------------------------------
// Persistent-wave MFMA GEMM, no LDS, no barriers.
// Each wave owns independent 16-row tiles (grid-stride), double-buffered in
// registers. Math: out = (xh + xl) @ bf16rne(Wsum) + bsum   (2-term split;
// dropped x@wl term ~2^-9 rel). A-frags loaded straight from global x.
// Rows with an inactive case: MFMA store predicated off, exact fp32 recompute.
// ---------------------------------------------------------------------------
__global__ __launch_bounds__(256, 4) void guarded_layer(
    const float* __restrict__ x, const float* __restrict__ presence,
    const float* __restrict__ W, const float* __restrict__ b,
    const float* __restrict__ ws, float* __restrict__ out, int N) {
  const float* wsum = ws;
  const float* bsum = ws + D * D;
  const unsigned short* WhT = (const unsigned short*)(ws + D * D + D);

  const int tid = threadIdx.x;
  const int lane = tid & 63;
  const int n_l = lane & 15;  // A row / C col within 16-tile
  const int kg = lane >> 4;   // k-group
  const long long Nm1 = (long long)N - 1;
  const long long tiles = ((long long)N + 15) >> 4;
  const long long wid = (long long)blockIdx.x * 4 + (tid >> 6);
  const long long nw = (long long)gridDim.x * 4;

  // ---- resident B fragments + bias (L2-hot, 8.5 KB total) ----
  short8 bh[4][2];
  float bs[4];
#pragma unroll
  for (int nt = 0; nt < 4; ++nt) {
    bs[nt] = bsum[nt * 16 + n_l];
#pragma unroll
    for (int kb = 0; kb < 2; ++kb)
      bh[nt][kb] = *reinterpret_cast<const short8*>(WhT + (nt * 16 + n_l) * D + kb * 32 + kg * 8);
  }

  float4 xa[4], xb[4], pa, pb;

  auto issue_load = [&](float4 (&xv)[4], float4& pv, long long t) {
    long long row0 = t << 4;
    long long xrow = row0 + n_l;
    if (xrow > Nm1) xrow = Nm1;  // clamp: duplicate, never stored
    const char* xbp = (const char*)x + xrow * 256 + kg * 32;
    xv[0] = *reinterpret_cast<const float4*>(xbp);
    xv[1] = *reinterpret_cast<const float4*>(xbp + 16);
    xv[2] = *reinterpret_cast<const float4*>(xbp + 128);
    xv[3] = *reinterpret_cast<const float4*>(xbp + 144);
    long long prow = row0 + ((lane & 31) >> 1);  // lanes 32-63 mirror 0-31
    if (prow > Nm1) prow = Nm1;
    pv = *reinterpret_cast<const float4*>((const char*)presence + prow * 32 + (lane & 1) * 16);
  };

  auto compute = [&](float4 (&xv)[4], float4& pv, long long t) {
    long long row0 = t << 4;
    // per-row inactive flags, fully in-register (bits 2r,2r+1 of ballot)
    float m0 = fminf(fminf(pv.x, pv.y), fminf(pv.z, pv.w));
    float rowmin = fminf(m0, __shfl_xor(m0, 1));
    unsigned int mlo = (unsigned int)__ballot(!(rowmin > EPS));

    f32x4 acc[4];
#pragma unroll
    for (int nt = 0; nt < 4; ++nt) acc[nt] = (f32x4){bs[nt], bs[nt], bs[nt], bs[nt]};

#pragma unroll
    for (int kb = 0; kb < 2; ++kb) {
      float f[8] = {xv[2 * kb].x, xv[2 * kb].y, xv[2 * kb].z, xv[2 * kb].w,
                    xv[2 * kb + 1].x, xv[2 * kb + 1].y, xv[2 * kb + 1].z, xv[2 * kb + 1].w};
      union { unsigned int u[4]; short8 s; } hi, lo;
#pragma unroll
      for (int q = 0; q < 4; ++q) {
        unsigned int b0 = __float_as_uint(f[2 * q]);
        unsigned int b1 = __float_as_uint(f[2 * q + 1]);
        hi.u[q] = (b0 >> 16) | (b1 & 0xffff0000u);
        float r0 = f[2 * q] - __uint_as_float(b0 & 0xffff0000u);      // exact
        float r1 = f[2 * q + 1] - __uint_as_float(b1 & 0xffff0000u);  // exact
        lo.u[q] = (__float_as_uint(r0) >> 16) | (__float_as_uint(r1) & 0xffff0000u);
      }
#pragma unroll
      for (int nt = 0; nt < 4; ++nt) {
        acc[nt] = __builtin_amdgcn_mfma_f32_16x16x32_bf16(hi.s, bh[nt][kb], acc[nt], 0, 0, 0);
        acc[nt] = __builtin_amdgcn_mfma_f32_16x16x32_bf16(lo.s, bh[nt][kb], acc[nt], 0, 0, 0);
      }
    }

    // store: C row = kg*4+rg, col = nt*16+n_l (m89-verified layout)
#pragma unroll
    for (int rg = 0; rg < 4; ++rg) {
      int tr = kg * 4 + rg;
      long long row = row0 + tr;
      bool ok = (row < (long long)N) && !((mlo >> (2 * tr)) & 1);
#pragma unroll
      for (int nt = 0; nt < 4; ++nt)
        if (ok) __builtin_nontemporal_store(acc[nt][rg], out + row * D + nt * 16 + n_l);
    }

    // rare (~8e-4 of rows): exact fp32 recompute, whole wave per row
    if (mlo != 0) {
#pragma unroll 1
      for (int r = 0; r < 16; ++r) {
        if ((mlo >> (2 * r)) & 1) {
          long long row = row0 + r;
          if (row >= (long long)N) break;
          const float* xr = x + row * D;
          float a = bsum[lane];
#pragma unroll 1
          for (int i = 0; i < D; ++i) a = fmaf(xr[i], wsum[i * D + lane], a);
#pragma unroll 1
          for (int c = 0; c < NCASES; ++c) {
            if (!(presence[row * NCASES + c] > EPS)) {
              a -= b[c * D + lane];
              const float* Wc = W + c * D * D;
#pragma unroll 1
              for (int i = 0; i < D; ++i) a = fmaf(-xr[i], Wc[i * D + lane], a);
            }
          }
          out[row * D + lane] = a;
        }
      }
    }
  };

  // ---- register ping-pong over grid-strided tiles ----
  long long t = wid;
  if (t >= tiles) return;
  issue_load(xa, pa, t);
  while (true) {
    long long t2 = t + nw;
    bool more = (t2 < tiles);
    if (more) issue_load(xb, pb, t2);
    compute(xa, pa, t);
    if (!more) break;
    long long t3 = t2 + nw;
    bool more2 = (t3 < tiles);
    if (more2) issue_load(xa, pa, t3);
    compute(xb, pb, t2);
    if (!more2) break;
    t = t3;
  }
}

extern "C" void kernel_launch(void* const* d_in, const int* in_sizes, int n_in,
                              void* d_out, int out_size, void* d_ws, size_t ws_size,
                              hipStream_t stream) {
  const float* x = (const float*)d_in[0];
  const float* presence = (const float*)d_in[1];
  const float* W = (const float*)d_in[2];
  const float* b = (const float*)d_in[3];
  float* out = (float*)d_out;
  float* ws = (float*)d_ws;

  int N = in_sizes[0] / D;

  prep_sums<<<(D * D + D + 255) / 256, 256, 0, stream>>>(W, b, ws);

  guarded_layer<<<NBLOCKS, 256, 0, stream>>>(x, presence, W, b, ws, out, N);
}